// Round 7
// baseline (379.088 us; speedup 1.0000x reference)
//
#include <hip/hip_runtime.h>
#include <cmath>

typedef __attribute__((ext_vector_type(8))) short short8;
typedef __attribute__((ext_vector_type(4))) float f32x4;
typedef __attribute__((ext_vector_type(4))) unsigned short us4;
typedef unsigned short u16;

#define BATCH 8192
#define HDIM  256
static constexpr size_t BH = (size_t)BATCH * HDIM;  // 2,097,152

__device__ __forceinline__ u16 f2bf(float f) {
    union { float f; unsigned u; } v; v.f = f;
    unsigned r = v.u + 0x7FFFu + ((v.u >> 16) & 1u);
    return (u16)(r >> 16);
}
__device__ __forceinline__ float bf2f(u16 u) {
    union { unsigned u; float f; } v; v.u = ((unsigned)u) << 16;
    return v.f;
}
__device__ __forceinline__ float sigmoidf_(float x) {
    return 1.f / (1.f + __expf(-x));
}
__device__ __forceinline__ short8 cvt8(const float* p) {
    f32x4 lo = *(const f32x4*)p, hi = *(const f32x4*)(p + 4);
    short8 t;
    t[0] = (short)f2bf(lo[0]); t[1] = (short)f2bf(lo[1]);
    t[2] = (short)f2bf(lo[2]); t[3] = (short)f2bf(lo[3]);
    t[4] = (short)f2bf(hi[0]); t[5] = (short)f2bf(hi[1]);
    t[6] = (short)f2bf(hi[2]); t[7] = (short)f2bf(hi[3]);
    return t;
}
__device__ __forceinline__ float dot4(const f32x4& a, const float* b) {
    return a[0] * b[0] + a[1] * b[1] + a[2] * b[2] + a[3] * b[3];
}

// ---------------- weight conversion: pack all needed weights to bf16 ----------------
// dst layout (u16 units, 65536 per chunk):
//  c0: embed_w | c1..4: wtn[l] | c5..8: wsn[l] | c9..12: wt[l][512:768]
//  c13..16: ws[l][0:256] | c17..20: ws[l][512:768] | c21: out_w
__global__ __launch_bounds__(256) void convert_weights(
    const float* __restrict__ embed_w, const float* __restrict__ wtn,
    const float* __restrict__ wsn, const float* __restrict__ wt,
    const float* __restrict__ ws, const float* __restrict__ out_w,
    u16* __restrict__ dst)
{
    int idx = blockIdx.x * 256 + threadIdx.x;
    int e = idx * 4;
    if (e >= 22 * 65536) return;
    int c = e >> 16, o = e & 65535;
    const float* src;
    if (c == 0)      src = embed_w + o;
    else if (c < 5)  src = wtn + (size_t)(c - 1) * 65536 + o;
    else if (c < 9)  src = wsn + (size_t)(c - 5) * 65536 + o;
    else if (c < 13) src = wt + (size_t)(c - 9) * 768 * 256 + 512 * 256 + o;
    else if (c < 17) src = ws + (size_t)(c - 13) * 768 * 256 + o;
    else if (c < 21) src = ws + (size_t)(c - 17) * 768 * 256 + 512 * 256 + o;
    else             src = out_w + o;
    f32x4 v = *(const f32x4*)src;
    us4 r;
#pragma unroll
    for (int j = 0; j < 4; ++j) r[j] = f2bf(v[j]);
    *(us4*)(dst + e) = r;
}

// ---------------- embed: S0 = x @ embed_w^T + b ----------------
// 512 thr (8 waves), 16 rows x 256 cols per block; wave w -> cols 32w..32w+31.
__global__ __launch_bounds__(512, 4) void gemm_embed(
    const float* __restrict__ x, const u16* __restrict__ W,
    const float* __restrict__ bias, u16* __restrict__ S0)
{
    const int lane = threadIdx.x & 63, wave = threadIdx.x >> 6;
    const int lr = lane & 15, kg = lane >> 4;
    const int row0 = blockIdx.x * 16;
    const int n0 = wave * 32;
    f32x4 acc[2] = {};
    for (int k0 = 0; k0 < 256; k0 += 32) {
        int k = k0 + kg * 8;
        short8 a = cvt8(x + (size_t)(row0 + lr) * 256 + k);
#pragma unroll
        for (int nf = 0; nf < 2; ++nf) {
            short8 b = *(const short8*)(W + (size_t)(n0 + nf * 16 + lr) * 256 + k);
            acc[nf] = __builtin_amdgcn_mfma_f32_16x16x32_bf16(a, b, acc[nf], 0, 0, 0);
        }
    }
#pragma unroll
    for (int nf = 0; nf < 2; ++nf) {
        int n = n0 + nf * 16 + lr;
        float bn = bias[n];
#pragma unroll
        for (int r = 0; r < 4; ++r)
            S0[(size_t)(row0 + kg * 4 + r) * 256 + n] = f2bf(acc[nf][r] + bn);
    }
}

// ---------------- out = tanh(S4 @ out_w^T + b), f32 ----------------
__global__ __launch_bounds__(512, 4) void gemm_out(
    const u16* __restrict__ S4, const u16* __restrict__ W,
    const float* __restrict__ bias, float* __restrict__ outp)
{
    const int lane = threadIdx.x & 63, wave = threadIdx.x >> 6;
    const int lr = lane & 15, kg = lane >> 4;
    const int row0 = blockIdx.x * 16;
    const int n0 = wave * 32;
    f32x4 acc[2] = {};
    for (int k0 = 0; k0 < 256; k0 += 32) {
        int k = k0 + kg * 8;
        short8 a = *(const short8*)(S4 + (size_t)(row0 + lr) * 256 + k);
#pragma unroll
        for (int nf = 0; nf < 2; ++nf) {
            short8 b = *(const short8*)(W + (size_t)(n0 + nf * 16 + lr) * 256 + k);
            acc[nf] = __builtin_amdgcn_mfma_f32_16x16x32_bf16(a, b, acc[nf], 0, 0, 0);
        }
    }
#pragma unroll
    for (int nf = 0; nf < 2; ++nf) {
        int n = n0 + nf * 16 + lr;
        float bn = bias[n];
#pragma unroll
        for (int r = 0; r < 4; ++r)
            outp[(size_t)(row0 + kg * 4 + r) * 256 + n] = tanhf(acc[nf][r] + bn);
    }
}

// ---------------- dual GEMM: s_next (waves 0-3) / t_next (waves 4-7) ----------------
// 512 thr, 16 rows x 256 cols per output; wave owns 64 cols of one output.
__global__ __launch_bounds__(512, 4) void gemm_dual(
    const u16* __restrict__ Scur, const float* __restrict__ Tlast,
    const u16* __restrict__ Wsn, const u16* __restrict__ Wtn,
    const float* __restrict__ bsn_l, const float* __restrict__ btn_l,
    u16* __restrict__ sn_g, u16* __restrict__ tn_g)
{
    const int lane = threadIdx.x & 63, wave = threadIdx.x >> 6;
    const int lr = lane & 15, kg = lane >> 4;
    const int row0 = blockIdx.x * 16;
    const int g = wave >> 2;          // 0: s_next, 1: t_next
    const int n0 = (wave & 3) * 64;
    const u16* Wm = g ? Wtn : Wsn;
    f32x4 acc[4] = {};
    for (int k0 = 0; k0 < 256; k0 += 32) {
        int k = k0 + kg * 8;
        short8 a;
        if (g == 0) a = *(const short8*)(Scur + (size_t)(row0 + lr) * 256 + k);
        else        a = cvt8(Tlast + (size_t)(row0 + lr) * 256 + k);
#pragma unroll
        for (int nf = 0; nf < 4; ++nf) {
            short8 b = *(const short8*)(Wm + (size_t)(n0 + nf * 16 + lr) * 256 + k);
            acc[nf] = __builtin_amdgcn_mfma_f32_16x16x32_bf16(a, b, acc[nf], 0, 0, 0);
        }
    }
    const float* bias = g ? btn_l : bsn_l;
    u16* dst = g ? tn_g : sn_g;
#pragma unroll
    for (int nf = 0; nf < 4; ++nf) {
        int n = n0 + nf * 16 + lr;
        float bn = bias[n];
#pragma unroll
        for (int r = 0; r < 4; ++r)
            dst[(size_t)(row0 + kg * 4 + r) * 256 + n] = f2bf(acc[nf][r] + bn);
    }
}

// ---------------- triple GEMM + gated combine ----------------
// 512 thr (8 waves), 16 rows; wave w -> cols 32w..32w+31 of all 3 matrices.
__global__ __launch_bounds__(512, 4) void gemm_triple(
    const u16* __restrict__ Tf, const u16* __restrict__ Sf,
    const u16* __restrict__ Wt3, const u16* __restrict__ Ws1, const u16* __restrict__ Ws3,
    const float* __restrict__ b1p, const float* __restrict__ b2p, const float* __restrict__ b3p,
    u16* __restrict__ Sout)
{
    const int lane = threadIdx.x & 63, wave = threadIdx.x >> 6;
    const int lr = lane & 15, kg = lane >> 4;
    const int row0 = blockIdx.x * 16;
    const int n0 = wave * 32;
    f32x4 aT[2] = {}, aG[2] = {}, aS[2] = {};
    for (int k0 = 0; k0 < 256; k0 += 32) {
        int k = k0 + kg * 8;
        short8 at = *(const short8*)(Tf + (size_t)(row0 + lr) * 256 + k);
        short8 as = *(const short8*)(Sf + (size_t)(row0 + lr) * 256 + k);
#pragma unroll
        for (int nf = 0; nf < 2; ++nf) {
            size_t wo = (size_t)(n0 + nf * 16 + lr) * 256 + k;
            aT[nf] = __builtin_amdgcn_mfma_f32_16x16x32_bf16(at, *(const short8*)(Wt3 + wo), aT[nf], 0, 0, 0);
            aG[nf] = __builtin_amdgcn_mfma_f32_16x16x32_bf16(as, *(const short8*)(Ws1 + wo), aG[nf], 0, 0, 0);
            aS[nf] = __builtin_amdgcn_mfma_f32_16x16x32_bf16(as, *(const short8*)(Ws3 + wo), aS[nf], 0, 0, 0);
        }
    }
#pragma unroll
    for (int nf = 0; nf < 2; ++nf) {
        int n = n0 + nf * 16 + lr;
        float bb1 = b1p[n], bb2 = b2p[n], bb3 = b3p[n];
#pragma unroll
        for (int r = 0; r < 4; ++r) {
            float gv = sigmoidf_(aG[nf][r] + bb2);
            float v = gv * (aS[nf][r] + bb3) + (1.f - gv) * (aT[nf][r] + bb1);
            Sout[(size_t)(row0 + kg * 4 + r) * 256 + n] = f2bf(v);
        }
    }
}

// ---------------- attention: one wave per row, vectorized butterfly ----------------
// grid 2048 x 256 thr (4 waves/block, 4 rows/block). Two load windows:
//  W1: sav[7], tav7, spatial keys/values, sn/tn/Sc  -> per-lane partial dots
//  W2: tav[0..6] issued BEFORE the butterfly, consumed after softmax.
// One 6-level __shfl_xor butterfly reduces all NV dot values simultaneously.
template<int LAYER>
__global__ __launch_bounds__(256, 4) void attn_k(
    const float* __restrict__ t_att, const float* __restrict__ s_att,
    const u16* __restrict__ S_hist,
    const u16* __restrict__ sn_g, const u16* __restrict__ tn_g,
    u16* __restrict__ tf_g, u16* __restrict__ sf_g)
{
    const int lane = threadIdx.x & 63;
    const int row = blockIdx.x * 4 + (threadIdx.x >> 6);
    const size_t ro = (size_t)row * 256 + lane * 4;
    const float scale = 0.0625f;  // 1/sqrt(256)

    const float* sa = s_att + (size_t)LAYER * 8 * BH + ro;
    const float* ta = t_att + (size_t)LAYER * 8 * BH + ro;

    // ---- window 1 loads ----
    f32x4 sav[7];
#pragma unroll
    for (int kk = 0; kk < 7; ++kk) sav[kk] = *(const f32x4*)(sa + (size_t)(kk + 1) * BH);
    f32x4 tav7 = *(const f32x4*)(ta + (size_t)7 * BH);
    f32x4 tspv[LAYER > 0 ? LAYER : 1];
    us4 shu[LAYER > 0 ? LAYER : 1];
#pragma unroll
    for (int jj = 0; jj < LAYER; ++jj) {
        tspv[jj] = *(const f32x4*)(t_att + ((size_t)jj * 8 + 7) * BH + ro);
        shu[jj]  = *(const us4*)(S_hist + (size_t)jj * BH + ro);
    }
    us4 scu = *(const us4*)(S_hist + (size_t)LAYER * BH + ro);
    us4 snu = *(const us4*)(sn_g + ro);
    us4 tnu = *(const us4*)(tn_g + ro);

    float sn[4], tn[4], Sc[4];
#pragma unroll
    for (int j = 0; j < 4; ++j) { sn[j] = bf2f(snu[j]); tn[j] = bf2f(tnu[j]); Sc[j] = bf2f(scu[j]); }

    // ---- per-lane partial dots: v[0..6]=sav·sn, v[7]=Sc·sn,
    //      v[8..8+LAYER-1]=tspv·tn, v[8+LAYER]=tav7·tn ----
    constexpr int NV = 9 + LAYER;
    float v[NV];
#pragma unroll
    for (int kk = 0; kk < 7; ++kk) v[kk] = dot4(sav[kk], sn);
    v[7] = Sc[0] * sn[0] + Sc[1] * sn[1] + Sc[2] * sn[2] + Sc[3] * sn[3];
#pragma unroll
    for (int jj = 0; jj < LAYER; ++jj) v[8 + jj] = dot4(tspv[jj], tn);
    v[8 + LAYER] = dot4(tav7, tn);

    // ---- window 2: issue tav[0..6] (latency hides under the butterfly) ----
    f32x4 tav[7];
#pragma unroll
    for (int kk = 0; kk < 7; ++kk) tav[kk] = *(const f32x4*)(ta + (size_t)kk * BH);

    // ---- single 6-level butterfly over all NV values ----
#pragma unroll
    for (int o = 32; o > 0; o >>= 1)
#pragma unroll
        for (int u = 0; u < NV; ++u) v[u] += __shfl_xor(v[u], o);

    // ---- temporal softmax + T_fusion ----
    float m = v[0] * scale;
#pragma unroll
    for (int kk = 1; kk < 8; ++kk) m = fmaxf(m, v[kk] * scale);
    float w8[8], den = 0.f;
#pragma unroll
    for (int kk = 0; kk < 8; ++kk) { w8[kk] = __expf(v[kk] * scale - m); den += w8[kk]; }
    float inv = 1.f / den;

    float Tt[4];
#pragma unroll
    for (int j = 0; j < 4; ++j) Tt[j] = w8[7] * tav7[j];
#pragma unroll
    for (int kk = 0; kk < 7; ++kk)
#pragma unroll
        for (int j = 0; j < 4; ++j) Tt[j] += w8[kk] * tav[kk][j];
    us4 ot;
#pragma unroll
    for (int j = 0; j < 4; ++j) {
        float g = sigmoidf_(tn[j]);
        ot[j] = f2bf(tav7[j] * g + (1.f - g) * Tt[j] * inv);
    }
    *(us4*)(tf_g + ro) = ot;

    // ---- spatial softmax (7-LAYER zero-logit zero-value entries) + S_fusion ----
    float ms = fmaxf(0.f, v[8 + LAYER] * scale);
#pragma unroll
    for (int jj = 0; jj < LAYER; ++jj) ms = fmaxf(ms, v[8 + jj] * scale);
    float dens = (float)(7 - LAYER) * __expf(-ms);
    float St[4];
    {
        float w = __expf(v[8 + LAYER] * scale - ms);
        dens += w;
#pragma unroll
        for (int j = 0; j < 4; ++j) St[j] = w * Sc[j];
    }
#pragma unroll
    for (int jj = 0; jj < LAYER; ++jj) {
        float w = __expf(v[8 + jj] * scale - ms);
        dens += w;
#pragma unroll
        for (int j = 0; j < 4; ++j) St[j] += w * bf2f(shu[jj][j]);
    }
    float invs = 1.f / dens;
    us4 os;
#pragma unroll
    for (int j = 0; j < 4; ++j) {
        float g = sigmoidf_(sn[j]);
        os[j] = f2bf(Sc[j] * g + (1.f - g) * St[j] * invs);
    }
    *(us4*)(sf_g + ro) = os;
}

extern "C" void kernel_launch(void* const* d_in, const int* in_sizes, int n_in,
                              void* d_out, int out_size, void* d_ws, size_t ws_size,
                              hipStream_t stream)
{
    (void)in_sizes; (void)n_in; (void)out_size; (void)ws_size;
    const float* x       = (const float*)d_in[0];
    const float* t_att   = (const float*)d_in[1];
    const float* s_att   = (const float*)d_in[2];
    const float* embed_w = (const float*)d_in[3];
    const float* embed_b = (const float*)d_in[4];
    const float* wtn     = (const float*)d_in[5];
    const float* btn     = (const float*)d_in[6];
    const float* wsn     = (const float*)d_in[7];
    const float* bsn     = (const float*)d_in[8];
    const float* wt      = (const float*)d_in[9];
    const float* bt      = (const float*)d_in[10];
    const float* ws_in   = (const float*)d_in[11];
    const float* bs      = (const float*)d_in[12];
    const float* out_w   = (const float*)d_in[13];
    const float* out_b   = (const float*)d_in[14];

    u16* wsp    = (u16*)d_ws;
    u16* Wbf    = wsp;                       // 22 * 65536 u16
    u16* S_hist = wsp + (size_t)22 * 65536;  // 5 * BH
    u16* sn_g   = S_hist + 5 * BH;
    u16* tn_g   = sn_g + BH;
    u16* tf_g   = tn_g + BH;
    u16* sf_g   = tf_g + BH;

    convert_weights<<<1408, 256, 0, stream>>>(embed_w, wtn, wsn, wt, ws_in, out_w, Wbf);

    gemm_embed<<<BATCH / 16, 512, 0, stream>>>(x, Wbf, embed_b, S_hist);

    for (int i = 0; i < 4; ++i) {
        gemm_dual<<<BATCH / 16, 512, 0, stream>>>(
            S_hist + (size_t)i * BH, t_att + ((size_t)i * 8 + 7) * BH,
            Wbf + (size_t)(5 + i) * 65536, Wbf + (size_t)(1 + i) * 65536,
            bsn + i * 256, btn + i * 256, sn_g, tn_g);

        switch (i) {
            case 0: attn_k<0><<<BATCH / 4, 256, 0, stream>>>(t_att, s_att, S_hist, sn_g, tn_g, tf_g, sf_g); break;
            case 1: attn_k<1><<<BATCH / 4, 256, 0, stream>>>(t_att, s_att, S_hist, sn_g, tn_g, tf_g, sf_g); break;
            case 2: attn_k<2><<<BATCH / 4, 256, 0, stream>>>(t_att, s_att, S_hist, sn_g, tn_g, tf_g, sf_g); break;
            case 3: attn_k<3><<<BATCH / 4, 256, 0, stream>>>(t_att, s_att, S_hist, sn_g, tn_g, tf_g, sf_g); break;
        }

        gemm_triple<<<BATCH / 16, 512, 0, stream>>>(
            tf_g, sf_g,
            Wbf + (size_t)(9 + i) * 65536,
            Wbf + (size_t)(13 + i) * 65536,
            Wbf + (size_t)(17 + i) * 65536,
            bt + i * 768 + 512, bs + i * 768, bs + i * 768 + 512,
            S_hist + (size_t)(i + 1) * BH);
    }

    gemm_out<<<BATCH / 16, 512, 0, stream>>>(
        S_hist + (size_t)4 * BH, Wbf + (size_t)21 * 65536, out_b, (float*)d_out);
}

// Round 8
// 278.252 us; speedup vs baseline: 1.3624x; 1.3624x over previous
//
#include <hip/hip_runtime.h>
#include <cmath>

typedef __attribute__((ext_vector_type(8))) short short8;
typedef __attribute__((ext_vector_type(4))) float f32x4;
typedef __attribute__((ext_vector_type(4))) unsigned short us4;
typedef unsigned short u16;

#define BATCH 8192
#define HDIM  256
static constexpr size_t BH = (size_t)BATCH * HDIM;  // 2,097,152

__device__ __forceinline__ u16 f2bf(float f) {
    union { float f; unsigned u; } v; v.f = f;
    unsigned r = v.u + 0x7FFFu + ((v.u >> 16) & 1u);
    return (u16)(r >> 16);
}
__device__ __forceinline__ float bf2f(u16 u) {
    union { unsigned u; float f; } v; v.u = ((unsigned)u) << 16;
    return v.f;
}
__device__ __forceinline__ float sigmoidf_(float x) {
    return 1.f / (1.f + __expf(-x));
}
__device__ __forceinline__ short8 cvt8(const float* p) {
    f32x4 lo = *(const f32x4*)p, hi = *(const f32x4*)(p + 4);
    short8 t;
    t[0] = (short)f2bf(lo[0]); t[1] = (short)f2bf(lo[1]);
    t[2] = (short)f2bf(lo[2]); t[3] = (short)f2bf(lo[3]);
    t[4] = (short)f2bf(hi[0]); t[5] = (short)f2bf(hi[1]);
    t[6] = (short)f2bf(hi[2]); t[7] = (short)f2bf(hi[3]);
    return t;
}
__device__ __forceinline__ float dot4(const f32x4& a, const float* b) {
    return a[0] * b[0] + a[1] * b[1] + a[2] * b[2] + a[3] * b[3];
}

// ---------------- weight conversion: pack all needed weights to bf16 ----------------
// dst layout (u16 units, 65536 per chunk):
//  c0: embed_w | c1..4: wtn[l] | c5..8: wsn[l] | c9..12: wt[l][512:768]
//  c13..16: ws[l][0:256] | c17..20: ws[l][512:768] | c21: out_w
__global__ __launch_bounds__(256) void convert_weights(
    const float* __restrict__ embed_w, const float* __restrict__ wtn,
    const float* __restrict__ wsn, const float* __restrict__ wt,
    const float* __restrict__ ws, const float* __restrict__ out_w,
    u16* __restrict__ dst)
{
    int idx = blockIdx.x * 256 + threadIdx.x;
    int e = idx * 4;
    if (e >= 22 * 65536) return;
    int c = e >> 16, o = e & 65535;
    const float* src;
    if (c == 0)      src = embed_w + o;
    else if (c < 5)  src = wtn + (size_t)(c - 1) * 65536 + o;
    else if (c < 9)  src = wsn + (size_t)(c - 5) * 65536 + o;
    else if (c < 13) src = wt + (size_t)(c - 9) * 768 * 256 + 512 * 256 + o;
    else if (c < 17) src = ws + (size_t)(c - 13) * 768 * 256 + o;
    else if (c < 21) src = ws + (size_t)(c - 17) * 768 * 256 + 512 * 256 + o;
    else             src = out_w + o;
    f32x4 v = *(const f32x4*)src;
    us4 r;
#pragma unroll
    for (int j = 0; j < 4; ++j) r[j] = f2bf(v[j]);
    *(us4*)(dst + e) = r;
}

// ---------------- mega kernel v4: 256 thr (4 waves), 16 rows, VGPR cap 256 ----------------
// launch_bounds(256,2): min 2 waves/SIMD -> allocator free up to 256 VGPR, so the
// attention phase can hold one full row's ~17 f32x4 loads in registers (no spill).
#define PAD 264  // u16 row stride (528 B)
__global__ __launch_bounds__(256, 2) void stau_mega(
    const float* __restrict__ x,
    const float* __restrict__ t_att, const float* __restrict__ s_att,
    const u16* __restrict__ Wbf,
    const float* __restrict__ embed_b,
    const float* __restrict__ btn, const float* __restrict__ bsn,
    const float* __restrict__ bt, const float* __restrict__ bs,
    const float* __restrict__ out_b,
    float* __restrict__ outp)
{
    __shared__ __align__(16) u16 S_lds[5][16][PAD];  // S history (bf16)
    __shared__ __align__(16) u16 sn_lds[16][PAD];
    __shared__ __align__(16) u16 tn_lds[16][PAD];
    __shared__ __align__(16) u16 tf_lds[16][PAD];
    __shared__ __align__(16) u16 sf_lds[16][PAD];

    const int lane = threadIdx.x & 63;
    const int wave = threadIdx.x >> 6;  // 0..3
    const int lr = lane & 15;
    const int kg = lane >> 4;
    const int row0 = blockIdx.x * 16;
    const float scale = 0.0625f;        // 1/sqrt(256)

    // ---- embed: S0 = x @ embed_w^T + embed_b (wave w -> cols 64w..64w+63) ----
    {
        const int n0 = wave * 64;
        f32x4 acc[4] = {};
        for (int k0 = 0; k0 < 256; k0 += 32) {
            int k = k0 + kg * 8;
            short8 a = cvt8(x + (size_t)(row0 + lr) * 256 + k);
#pragma unroll
            for (int nf = 0; nf < 4; ++nf) {
                short8 b = *(const short8*)(Wbf + (size_t)(n0 + nf * 16 + lr) * 256 + k);
                acc[nf] = __builtin_amdgcn_mfma_f32_16x16x32_bf16(a, b, acc[nf], 0, 0, 0);
            }
        }
#pragma unroll
        for (int nf = 0; nf < 4; ++nf) {
            int n = n0 + nf * 16 + lr;
            float bn = embed_b[n];
#pragma unroll
            for (int r = 0; r < 4; ++r)
                S_lds[0][kg * 4 + r][n] = f2bf(acc[nf][r] + bn);
        }
    }
    __syncthreads();

    for (int i = 0; i < 4; ++i) {
        // ---- phase 1: s_next (waves 0-1) / t_next (waves 2-3), 128 cols each ----
        {
            const int g = wave >> 1;          // 0: s_next, 1: t_next
            const int n0 = (wave & 1) * 128;
            const u16* Wm = Wbf + (size_t)((g ? 1 : 5) + i) * 65536;
            const float* bias = (g ? btn : bsn) + i * 256;
            f32x4 acc[8] = {};
            for (int k0 = 0; k0 < 256; k0 += 32) {
                int k = k0 + kg * 8;
                short8 a;
                if (g == 0) a = *(const short8*)(&S_lds[i][lr][k]);
                else        a = cvt8(t_att + ((size_t)i * 8 + 7) * BH + (size_t)(row0 + lr) * 256 + k);
#pragma unroll
                for (int nf = 0; nf < 8; ++nf) {
                    short8 b = *(const short8*)(Wm + (size_t)(n0 + nf * 16 + lr) * 256 + k);
                    acc[nf] = __builtin_amdgcn_mfma_f32_16x16x32_bf16(a, b, acc[nf], 0, 0, 0);
                }
            }
            u16 (*dst)[PAD] = g ? tn_lds : sn_lds;
#pragma unroll
            for (int nf = 0; nf < 8; ++nf) {
                int n = n0 + nf * 16 + lr;
                float bn = bias[n];
#pragma unroll
                for (int r = 0; r < 4; ++r)
                    dst[kg * 4 + r][n] = f2bf(acc[nf][r] + bn);
            }
        }
        __syncthreads();

        // ---- phase 2: attention + gating, wave w -> rows 4w..4w+3, fully batched ----
        for (int rr = wave * 4; rr < wave * 4 + 4; ++rr) {
            const size_t ro = (size_t)(row0 + rr) * 256 + lane * 4;
            const float* sa = s_att + (size_t)i * 8 * BH + ro;
            const float* ta = t_att + (size_t)i * 8 * BH + ro;

            // batch ALL of this row's global loads (VGPR budget 256 -> no spill)
            f32x4 sav[7], tav[8], tspv[3] = {};
#pragma unroll
            for (int kk = 0; kk < 7; ++kk) sav[kk] = *(const f32x4*)(sa + (size_t)(kk + 1) * BH);
#pragma unroll
            for (int kk = 0; kk < 8; ++kk) tav[kk] = *(const f32x4*)(ta + (size_t)kk * BH);
#pragma unroll
            for (int jj = 0; jj < 3; ++jj)
                if (jj < i) tspv[jj] = *(const f32x4*)(t_att + ((size_t)jj * 8 + 7) * BH + ro);

            us4 snu = *(const us4*)&sn_lds[rr][lane * 4];
            us4 tnu = *(const us4*)&tn_lds[rr][lane * 4];
            us4 scu = *(const us4*)&S_lds[i][rr][lane * 4];
            float sn[4], tn[4], Sc[4];
#pragma unroll
            for (int j = 0; j < 4; ++j) { sn[j] = bf2f(snu[j]); tn[j] = bf2f(tnu[j]); Sc[j] = bf2f(scu[j]); }

            // per-lane partial dots: v[0..6]=sav·sn, v[7]=Sc·sn, v[8..10]=tspv·tn, v[11]=tav7·tn
            float v[12];
#pragma unroll
            for (int kk = 0; kk < 7; ++kk) v[kk] = dot4(sav[kk], sn);
            v[7] = Sc[0] * sn[0] + Sc[1] * sn[1] + Sc[2] * sn[2] + Sc[3] * sn[3];
#pragma unroll
            for (int jj = 0; jj < 3; ++jj) v[8 + jj] = (jj < i) ? dot4(tspv[jj], tn) : 0.f;
            v[11] = dot4(tav[7], tn);

            // single 6-level butterfly over all 12 values
#pragma unroll
            for (int o = 32; o > 0; o >>= 1)
#pragma unroll
                for (int u = 0; u < 12; ++u) v[u] += __shfl_xor(v[u], o);

            // temporal softmax + T_fusion
            float m = v[0] * scale;
#pragma unroll
            for (int kk = 1; kk < 8; ++kk) m = fmaxf(m, v[kk] * scale);
            float w8[8], den = 0.f;
#pragma unroll
            for (int kk = 0; kk < 8; ++kk) { w8[kk] = __expf(v[kk] * scale - m); den += w8[kk]; }
            float inv = 1.f / den;

            float Tt[4] = {0.f, 0.f, 0.f, 0.f};
#pragma unroll
            for (int kk = 0; kk < 8; ++kk)
#pragma unroll
                for (int j = 0; j < 4; ++j) Tt[j] += w8[kk] * tav[kk][j];
            us4 ot;
#pragma unroll
            for (int j = 0; j < 4; ++j) {
                float g = sigmoidf_(tn[j]);
                ot[j] = f2bf(tav[7][j] * g + (1.f - g) * Tt[j] * inv);
            }
            *(us4*)&tf_lds[rr][lane * 4] = ot;

            // spatial softmax: keys = [zeros x (7-i), t_att[0,7]..t_att[i,7]]
            float ms = fmaxf(0.f, v[11] * scale);
#pragma unroll
            for (int jj = 0; jj < 3; ++jj)
                if (jj < i) ms = fmaxf(ms, v[8 + jj] * scale);
            float dens = (float)(7 - i) * __expf(-ms);
            float St[4];
            {
                float w = __expf(v[11] * scale - ms);
                dens += w;
#pragma unroll
                for (int j = 0; j < 4; ++j) St[j] = w * Sc[j];
            }
#pragma unroll
            for (int jj = 0; jj < 3; ++jj)
                if (jj < i) {
                    float w = __expf(v[8 + jj] * scale - ms);
                    dens += w;
                    us4 shu = *(const us4*)&S_lds[jj][rr][lane * 4];
#pragma unroll
                    for (int j = 0; j < 4; ++j) St[j] += w * bf2f(shu[j]);
                }
            float invs = 1.f / dens;
            us4 os;
#pragma unroll
            for (int j = 0; j < 4; ++j) {
                float g = sigmoidf_(sn[j]);
                os[j] = f2bf(Sc[j] * g + (1.f - g) * St[j] * invs);
            }
            *(us4*)&sf_lds[rr][lane * 4] = os;
        }
        __syncthreads();

        // ---- phase 3: triple GEMM + gated combine (wave w -> cols 64w..64w+63) ----
        {
            const int n0 = wave * 64;
            const u16* Wt3 = Wbf + (size_t)(9  + i) * 65536;
            const u16* Ws1 = Wbf + (size_t)(13 + i) * 65536;
            const u16* Ws3 = Wbf + (size_t)(17 + i) * 65536;
            f32x4 aT[4] = {}, aG[4] = {}, aS[4] = {};
            for (int k0 = 0; k0 < 256; k0 += 32) {
                int k = k0 + kg * 8;
                short8 at = *(const short8*)(&tf_lds[lr][k]);
                short8 as = *(const short8*)(&sf_lds[lr][k]);
#pragma unroll
                for (int nf = 0; nf < 4; ++nf) {
                    size_t wo = (size_t)(n0 + nf * 16 + lr) * 256 + k;
                    aT[nf] = __builtin_amdgcn_mfma_f32_16x16x32_bf16(at, *(const short8*)(Wt3 + wo), aT[nf], 0, 0, 0);
                    aG[nf] = __builtin_amdgcn_mfma_f32_16x16x32_bf16(as, *(const short8*)(Ws1 + wo), aG[nf], 0, 0, 0);
                    aS[nf] = __builtin_amdgcn_mfma_f32_16x16x32_bf16(as, *(const short8*)(Ws3 + wo), aS[nf], 0, 0, 0);
                }
            }
            const float* b1 = bt + i * 768 + 512;
            const float* b2 = bs + i * 768;
            const float* b3 = bs + i * 768 + 512;
#pragma unroll
            for (int nf = 0; nf < 4; ++nf) {
                int n = n0 + nf * 16 + lr;
                float bb1 = b1[n], bb2 = b2[n], bb3 = b3[n];
#pragma unroll
                for (int r = 0; r < 4; ++r) {
                    float gv = sigmoidf_(aG[nf][r] + bb2);
                    float vv = gv * (aS[nf][r] + bb3) + (1.f - gv) * (aT[nf][r] + bb1);
                    S_lds[i + 1][kg * 4 + r][n] = f2bf(vv);
                }
            }
        }
        __syncthreads();
    }

    // ---- out = tanh(S4 @ out_w^T + out_b), f32 ----
    {
        const int n0 = wave * 64;
        const u16* Wo = Wbf + (size_t)21 * 65536;
        f32x4 acc[4] = {};
        for (int k0 = 0; k0 < 256; k0 += 32) {
            int k = k0 + kg * 8;
            short8 a = *(const short8*)(&S_lds[4][lr][k]);
#pragma unroll
            for (int nf = 0; nf < 4; ++nf) {
                short8 b = *(const short8*)(Wo + (size_t)(n0 + nf * 16 + lr) * 256 + k);
                acc[nf] = __builtin_amdgcn_mfma_f32_16x16x32_bf16(a, b, acc[nf], 0, 0, 0);
            }
        }
#pragma unroll
        for (int nf = 0; nf < 4; ++nf) {
            int n = n0 + nf * 16 + lr;
            float bn = out_b[n];
#pragma unroll
            for (int r = 0; r < 4; ++r)
                outp[(size_t)(row0 + kg * 4 + r) * 256 + n] = tanhf(acc[nf][r] + bn);
        }
    }
}

extern "C" void kernel_launch(void* const* d_in, const int* in_sizes, int n_in,
                              void* d_out, int out_size, void* d_ws, size_t ws_size,
                              hipStream_t stream)
{
    (void)in_sizes; (void)n_in; (void)out_size; (void)ws_size;
    const float* x       = (const float*)d_in[0];
    const float* t_att   = (const float*)d_in[1];
    const float* s_att   = (const float*)d_in[2];
    const float* embed_w = (const float*)d_in[3];
    const float* embed_b = (const float*)d_in[4];
    const float* wtn     = (const float*)d_in[5];
    const float* btn     = (const float*)d_in[6];
    const float* wsn     = (const float*)d_in[7];
    const float* bsn     = (const float*)d_in[8];
    const float* wt      = (const float*)d_in[9];
    const float* bt      = (const float*)d_in[10];
    const float* ws_in   = (const float*)d_in[11];
    const float* bs      = (const float*)d_in[12];
    const float* out_w   = (const float*)d_in[13];
    const float* out_b   = (const float*)d_in[14];

    u16* Wbf = (u16*)d_ws;  // 22 * 65536 u16 = 2.88 MB

    convert_weights<<<1408, 256, 0, stream>>>(embed_w, wtn, wsn, wt, ws_in, out_w, Wbf);

    stau_mega<<<BATCH / 16, 256, 0, stream>>>(
        x, t_att, s_att, Wbf, embed_b, btn, bsn, bt, bs, out_b, (float*)d_out);
}

// Round 9
// 271.884 us; speedup vs baseline: 1.3943x; 1.0234x over previous
//
#include <hip/hip_runtime.h>
#include <cmath>

typedef __attribute__((ext_vector_type(8))) short short8;
typedef __attribute__((ext_vector_type(4))) float f32x4;
typedef __attribute__((ext_vector_type(4))) unsigned short us4;
typedef unsigned short u16;

#define BATCH 8192
#define HDIM  256
static constexpr size_t BH = (size_t)BATCH * HDIM;  // 2,097,152
#define PAD 264  // u16 LDS row stride (528 B)

__device__ __forceinline__ u16 f2bf(float f) {
    union { float f; unsigned u; } v; v.f = f;
    unsigned r = v.u + 0x7FFFu + ((v.u >> 16) & 1u);
    return (u16)(r >> 16);
}
__device__ __forceinline__ float bf2f(u16 u) {
    union { unsigned u; float f; } v; v.u = ((unsigned)u) << 16;
    return v.f;
}
__device__ __forceinline__ float sigmoidf_(float x) {
    return 1.f / (1.f + __expf(-x));
}
__device__ __forceinline__ short8 cvt8(const float* p) {
    f32x4 lo = *(const f32x4*)p, hi = *(const f32x4*)(p + 4);
    short8 t;
    t[0] = (short)f2bf(lo[0]); t[1] = (short)f2bf(lo[1]);
    t[2] = (short)f2bf(lo[2]); t[3] = (short)f2bf(lo[3]);
    t[4] = (short)f2bf(hi[0]); t[5] = (short)f2bf(hi[1]);
    t[6] = (short)f2bf(hi[2]); t[7] = (short)f2bf(hi[3]);
    return t;
}
__device__ __forceinline__ float dot4(const f32x4& a, const float* b) {
    return a[0] * b[0] + a[1] * b[1] + a[2] * b[2] + a[3] * b[3];
}
template<int N>
__device__ __forceinline__ void vmwait() {
    asm volatile("s_waitcnt vmcnt(%0)" :: "n"(N) : "memory");
    __builtin_amdgcn_sched_barrier(0);
}

// ---------------- weight conversion: pack all needed weights to bf16 ----------------
// dst layout (u16 units, 65536 per chunk):
//  c0: embed_w | c1..4: wtn[l] | c5..8: wsn[l] | c9..12: wt[l][512:768]
//  c13..16: ws[l][0:256] | c17..20: ws[l][512:768] | c21: out_w
__global__ __launch_bounds__(256) void convert_weights(
    const float* __restrict__ embed_w, const float* __restrict__ wtn,
    const float* __restrict__ wsn, const float* __restrict__ wt,
    const float* __restrict__ ws, const float* __restrict__ out_w,
    u16* __restrict__ dst)
{
    int idx = blockIdx.x * 256 + threadIdx.x;
    int e = idx * 4;
    if (e >= 22 * 65536) return;
    int c = e >> 16, o = e & 65535;
    const float* src;
    if (c == 0)      src = embed_w + o;
    else if (c < 5)  src = wtn + (size_t)(c - 1) * 65536 + o;
    else if (c < 9)  src = wsn + (size_t)(c - 5) * 65536 + o;
    else if (c < 13) src = wt + (size_t)(c - 9) * 768 * 256 + 512 * 256 + o;
    else if (c < 17) src = ws + (size_t)(c - 13) * 768 * 256 + o;
    else if (c < 21) src = ws + (size_t)(c - 17) * 768 * 256 + 512 * 256 + o;
    else             src = out_w + o;
    f32x4 v = *(const f32x4*)src;
    us4 r;
#pragma unroll
    for (int j = 0; j < 4; ++j) r[j] = f2bf(v[j]);
    *(us4*)(dst + e) = r;
}

// ---- phase 2 helpers: asm-issued load cluster + register-resident compute ----
template<int I>
__device__ __forceinline__ void issue_row(f32x4 (&buf)[18],
    const float* __restrict__ t_att, const float* __restrict__ s_att,
    int row, int lane)
{
    const size_t ro = (size_t)row * 256 + lane * 4;
    const float* sa = s_att + (size_t)I * 8 * BH + ro;
    const float* ta = t_att + (size_t)I * 8 * BH + ro;
#pragma unroll
    for (int kk = 0; kk < 7; ++kk)
        asm volatile("global_load_dwordx4 %0, %1, off"
                     : "=v"(buf[kk]) : "v"(sa + (size_t)(kk + 1) * BH));
#pragma unroll
    for (int kk = 0; kk < 8; ++kk)
        asm volatile("global_load_dwordx4 %0, %1, off"
                     : "=v"(buf[7 + kk]) : "v"(ta + (size_t)kk * BH));
#pragma unroll
    for (int jj = 0; jj < I; ++jj)
        asm volatile("global_load_dwordx4 %0, %1, off"
                     : "=v"(buf[15 + jj]) : "v"(t_att + ((size_t)jj * 8 + 7) * BH + ro));
}

template<int I>
__device__ __forceinline__ void compute_row(
    const f32x4 (&buf)[18], int rr, int lane,
    u16 (&S_lds)[5][16][PAD], u16 (&sn_lds)[16][PAD], u16 (&tn_lds)[16][PAD],
    u16 (&tf_lds)[16][PAD], u16 (&sf_lds)[16][PAD])
{
    const float scale = 0.0625f;  // 1/sqrt(256)
    us4 snu = *(const us4*)&sn_lds[rr][lane * 4];
    us4 tnu = *(const us4*)&tn_lds[rr][lane * 4];
    us4 scu = *(const us4*)&S_lds[I][rr][lane * 4];
    float sn[4], tn[4], Sc[4];
#pragma unroll
    for (int j = 0; j < 4; ++j) { sn[j] = bf2f(snu[j]); tn[j] = bf2f(tnu[j]); Sc[j] = bf2f(scu[j]); }

    // per-lane partial dots: v[0..6]=sav·sn, v[7]=Sc·sn, v[8..8+I-1]=tsp·tn, v[8+I]=tav7·tn
    constexpr int NV = 9 + I;
    float v[NV];
#pragma unroll
    for (int kk = 0; kk < 7; ++kk) v[kk] = dot4(buf[kk], sn);
    v[7] = Sc[0] * sn[0] + Sc[1] * sn[1] + Sc[2] * sn[2] + Sc[3] * sn[3];
#pragma unroll
    for (int jj = 0; jj < I; ++jj) v[8 + jj] = dot4(buf[15 + jj], tn);
    v[8 + I] = dot4(buf[14], tn);

    // single 6-level butterfly over all NV values
#pragma unroll
    for (int o = 32; o > 0; o >>= 1)
#pragma unroll
        for (int u = 0; u < NV; ++u) v[u] += __shfl_xor(v[u], o);

    // temporal softmax + T_fusion
    float m = v[0] * scale;
#pragma unroll
    for (int kk = 1; kk < 8; ++kk) m = fmaxf(m, v[kk] * scale);
    float w8[8], den = 0.f;
#pragma unroll
    for (int kk = 0; kk < 8; ++kk) { w8[kk] = __expf(v[kk] * scale - m); den += w8[kk]; }
    float inv = 1.f / den;

    float Tt[4] = {0.f, 0.f, 0.f, 0.f};
#pragma unroll
    for (int kk = 0; kk < 8; ++kk)
#pragma unroll
        for (int j = 0; j < 4; ++j) Tt[j] += w8[kk] * buf[7 + kk][j];
    us4 ot;
#pragma unroll
    for (int j = 0; j < 4; ++j) {
        float g = sigmoidf_(tn[j]);
        ot[j] = f2bf(buf[14][j] * g + (1.f - g) * Tt[j] * inv);
    }
    *(us4*)&tf_lds[rr][lane * 4] = ot;

    // spatial softmax: keys = [zeros x (7-I), t_att[0,7]..t_att[I,7]]
    float ms = fmaxf(0.f, v[8 + I] * scale);
#pragma unroll
    for (int jj = 0; jj < I; ++jj) ms = fmaxf(ms, v[8 + jj] * scale);
    float dens = (float)(7 - I) * __expf(-ms);
    float St[4];
    {
        float w = __expf(v[8 + I] * scale - ms);
        dens += w;
#pragma unroll
        for (int j = 0; j < 4; ++j) St[j] = w * Sc[j];
    }
#pragma unroll
    for (int jj = 0; jj < I; ++jj) {
        float w = __expf(v[8 + jj] * scale - ms);
        dens += w;
        us4 shu = *(const us4*)&S_lds[jj][rr][lane * 4];
#pragma unroll
        for (int j = 0; j < 4; ++j) St[j] += w * bf2f(shu[j]);
    }
    float invs = 1.f / dens;
    us4 os;
#pragma unroll
    for (int j = 0; j < 4; ++j) {
        float g = sigmoidf_(sn[j]);
        os[j] = f2bf(Sc[j] * g + (1.f - g) * St[j] * invs);
    }
    *(us4*)&sf_lds[rr][lane * 4] = os;
}

template<int I>
__device__ __forceinline__ void layer_body(
    const float* __restrict__ t_att, const float* __restrict__ s_att,
    const u16* __restrict__ Wbf,
    const float* __restrict__ btn, const float* __restrict__ bsn,
    const float* __restrict__ bt, const float* __restrict__ bs,
    u16 (&S_lds)[5][16][PAD], u16 (&sn_lds)[16][PAD], u16 (&tn_lds)[16][PAD],
    u16 (&tf_lds)[16][PAD], u16 (&sf_lds)[16][PAD],
    int lane, int wave, int lr, int kg, int row0)
{
    // ---- phase 1: s_next (waves 0-1) / t_next (waves 2-3), 128 cols each ----
    {
        const int g = wave >> 1;
        const int n0 = (wave & 1) * 128;
        const u16* Wm = Wbf + (size_t)((g ? 1 : 5) + I) * 65536;
        const float* bias = (g ? btn : bsn) + I * 256;
        f32x4 acc[8] = {};
        for (int k0 = 0; k0 < 256; k0 += 32) {
            int k = k0 + kg * 8;
            short8 a;
            if (g == 0) a = *(const short8*)(&S_lds[I][lr][k]);
            else        a = cvt8(t_att + ((size_t)I * 8 + 7) * BH + (size_t)(row0 + lr) * 256 + k);
#pragma unroll
            for (int nf = 0; nf < 8; ++nf) {
                short8 b = *(const short8*)(Wm + (size_t)(n0 + nf * 16 + lr) * 256 + k);
                acc[nf] = __builtin_amdgcn_mfma_f32_16x16x32_bf16(a, b, acc[nf], 0, 0, 0);
            }
        }
        u16 (*dst)[PAD] = g ? tn_lds : sn_lds;
#pragma unroll
        for (int nf = 0; nf < 8; ++nf) {
            int n = n0 + nf * 16 + lr;
            float bn = bias[n];
#pragma unroll
            for (int r = 0; r < 4; ++r)
                dst[kg * 4 + r][n] = f2bf(acc[nf][r] + bn);
        }
    }
    __syncthreads();

    // ---- phase 2: attention, 2-deep asm-pipelined rows (counted vmcnt, never drain early) ----
    {
        constexpr int NL = 15 + I;
        const int r0 = wave * 4;
        f32x4 A[18], B[18];
        issue_row<I>(A, t_att, s_att, row0 + r0, lane);
        issue_row<I>(B, t_att, s_att, row0 + r0 + 1, lane);
        vmwait<NL>();
        compute_row<I>(A, r0, lane, S_lds, sn_lds, tn_lds, tf_lds, sf_lds);
        issue_row<I>(A, t_att, s_att, row0 + r0 + 2, lane);
        vmwait<NL>();
        compute_row<I>(B, r0 + 1, lane, S_lds, sn_lds, tn_lds, tf_lds, sf_lds);
        issue_row<I>(B, t_att, s_att, row0 + r0 + 3, lane);
        vmwait<NL>();
        compute_row<I>(A, r0 + 2, lane, S_lds, sn_lds, tn_lds, tf_lds, sf_lds);
        vmwait<0>();
        compute_row<I>(B, r0 + 3, lane, S_lds, sn_lds, tn_lds, tf_lds, sf_lds);
    }
    __syncthreads();

    // ---- phase 3: triple GEMM + gated combine (wave w -> cols 64w..64w+63) ----
    {
        const int n0 = wave * 64;
        const u16* Wt3 = Wbf + (size_t)(9  + I) * 65536;
        const u16* Ws1 = Wbf + (size_t)(13 + I) * 65536;
        const u16* Ws3 = Wbf + (size_t)(17 + I) * 65536;
        f32x4 aT[4] = {}, aG[4] = {}, aS[4] = {};
        for (int k0 = 0; k0 < 256; k0 += 32) {
            int k = k0 + kg * 8;
            short8 at = *(const short8*)(&tf_lds[lr][k]);
            short8 as = *(const short8*)(&sf_lds[lr][k]);
#pragma unroll
            for (int nf = 0; nf < 4; ++nf) {
                size_t wo = (size_t)(n0 + nf * 16 + lr) * 256 + k;
                aT[nf] = __builtin_amdgcn_mfma_f32_16x16x32_bf16(at, *(const short8*)(Wt3 + wo), aT[nf], 0, 0, 0);
                aG[nf] = __builtin_amdgcn_mfma_f32_16x16x32_bf16(as, *(const short8*)(Ws1 + wo), aG[nf], 0, 0, 0);
                aS[nf] = __builtin_amdgcn_mfma_f32_16x16x32_bf16(as, *(const short8*)(Ws3 + wo), aS[nf], 0, 0, 0);
            }
        }
        const float* b1 = bt + I * 768 + 512;
        const float* b2 = bs + I * 768;
        const float* b3 = bs + I * 768 + 512;
#pragma unroll
        for (int nf = 0; nf < 4; ++nf) {
            int n = n0 + nf * 16 + lr;
            float bb1 = b1[n], bb2 = b2[n], bb3 = b3[n];
#pragma unroll
            for (int r = 0; r < 4; ++r) {
                float gv = sigmoidf_(aG[nf][r] + bb2);
                float vv = gv * (aS[nf][r] + bb3) + (1.f - gv) * (aT[nf][r] + bb1);
                S_lds[I + 1][kg * 4 + r][n] = f2bf(vv);
            }
        }
    }
    __syncthreads();
}

// ---------------- mega kernel v5: 256 thr (4 waves), 16 rows, asm-pipelined attention ----------------
__global__ __launch_bounds__(256, 2) void stau_mega(
    const float* __restrict__ x,
    const float* __restrict__ t_att, const float* __restrict__ s_att,
    const u16* __restrict__ Wbf,
    const float* __restrict__ embed_b,
    const float* __restrict__ btn, const float* __restrict__ bsn,
    const float* __restrict__ bt, const float* __restrict__ bs,
    const float* __restrict__ out_b,
    float* __restrict__ outp)
{
    __shared__ __align__(16) u16 S_lds[5][16][PAD];
    __shared__ __align__(16) u16 sn_lds[16][PAD];
    __shared__ __align__(16) u16 tn_lds[16][PAD];
    __shared__ __align__(16) u16 tf_lds[16][PAD];
    __shared__ __align__(16) u16 sf_lds[16][PAD];

    const int lane = threadIdx.x & 63;
    const int wave = threadIdx.x >> 6;  // 0..3
    const int lr = lane & 15;
    const int kg = lane >> 4;
    const int row0 = blockIdx.x * 16;

    // ---- embed: S0 = x @ embed_w^T + embed_b (wave w -> cols 64w..64w+63) ----
    {
        const int n0 = wave * 64;
        f32x4 acc[4] = {};
        for (int k0 = 0; k0 < 256; k0 += 32) {
            int k = k0 + kg * 8;
            short8 a = cvt8(x + (size_t)(row0 + lr) * 256 + k);
#pragma unroll
            for (int nf = 0; nf < 4; ++nf) {
                short8 b = *(const short8*)(Wbf + (size_t)(n0 + nf * 16 + lr) * 256 + k);
                acc[nf] = __builtin_amdgcn_mfma_f32_16x16x32_bf16(a, b, acc[nf], 0, 0, 0);
            }
        }
#pragma unroll
        for (int nf = 0; nf < 4; ++nf) {
            int n = n0 + nf * 16 + lr;
            float bn = embed_b[n];
#pragma unroll
            for (int r = 0; r < 4; ++r)
                S_lds[0][kg * 4 + r][n] = f2bf(acc[nf][r] + bn);
        }
    }
    __syncthreads();

    layer_body<0>(t_att, s_att, Wbf, btn, bsn, bt, bs,
                  S_lds, sn_lds, tn_lds, tf_lds, sf_lds, lane, wave, lr, kg, row0);
    layer_body<1>(t_att, s_att, Wbf, btn, bsn, bt, bs,
                  S_lds, sn_lds, tn_lds, tf_lds, sf_lds, lane, wave, lr, kg, row0);
    layer_body<2>(t_att, s_att, Wbf, btn, bsn, bt, bs,
                  S_lds, sn_lds, tn_lds, tf_lds, sf_lds, lane, wave, lr, kg, row0);
    layer_body<3>(t_att, s_att, Wbf, btn, bsn, bt, bs,
                  S_lds, sn_lds, tn_lds, tf_lds, sf_lds, lane, wave, lr, kg, row0);

    // ---- out = tanh(S4 @ out_w^T + out_b), f32 ----
    {
        const int n0 = wave * 64;
        const u16* Wo = Wbf + (size_t)21 * 65536;
        f32x4 acc[4] = {};
        for (int k0 = 0; k0 < 256; k0 += 32) {
            int k = k0 + kg * 8;
            short8 a = *(const short8*)(&S_lds[4][lr][k]);
#pragma unroll
            for (int nf = 0; nf < 4; ++nf) {
                short8 b = *(const short8*)(Wo + (size_t)(n0 + nf * 16 + lr) * 256 + k);
                acc[nf] = __builtin_amdgcn_mfma_f32_16x16x32_bf16(a, b, acc[nf], 0, 0, 0);
            }
        }
#pragma unroll
        for (int nf = 0; nf < 4; ++nf) {
            int n = n0 + nf * 16 + lr;
            float bn = out_b[n];
#pragma unroll
            for (int r = 0; r < 4; ++r)
                outp[(size_t)(row0 + kg * 4 + r) * 256 + n] = tanhf(acc[nf][r] + bn);
        }
    }
}

extern "C" void kernel_launch(void* const* d_in, const int* in_sizes, int n_in,
                              void* d_out, int out_size, void* d_ws, size_t ws_size,
                              hipStream_t stream)
{
    (void)in_sizes; (void)n_in; (void)out_size; (void)ws_size;
    const float* x       = (const float*)d_in[0];
    const float* t_att   = (const float*)d_in[1];
    const float* s_att   = (const float*)d_in[2];
    const float* embed_w = (const float*)d_in[3];
    const float* embed_b = (const float*)d_in[4];
    const float* wtn     = (const float*)d_in[5];
    const float* btn     = (const float*)d_in[6];
    const float* wsn     = (const float*)d_in[7];
    const float* bsn     = (const float*)d_in[8];
    const float* wt      = (const float*)d_in[9];
    const float* bt      = (const float*)d_in[10];
    const float* ws_in   = (const float*)d_in[11];
    const float* bs      = (const float*)d_in[12];
    const float* out_w   = (const float*)d_in[13];
    const float* out_b   = (const float*)d_in[14];

    u16* Wbf = (u16*)d_ws;  // 22 * 65536 u16 = 2.88 MB

    convert_weights<<<1408, 256, 0, stream>>>(embed_w, wtn, wsn, wt, ws_in, out_w, Wbf);

    stau_mega<<<BATCH / 16, 256, 0, stream>>>(
        x, t_att, s_att, Wbf, embed_b, btn, bsn, bt, bs, out_b, (float*)d_out);
}